// Round 3
// baseline (680.428 us; speedup 1.0000x reference)
//
#include <hip/hip_runtime.h>
#include <math.h>

#define BB 4
#define NN 4096
#define DD 64
#define KK 8
#define CH 4                    // j-chunks per row: grid = 4*64*4 = 1024 blocks
#define NT ((NN / CH) / 64)     // 16 j-tiles per block

__device__ __forceinline__ float tau_of(const float* __restrict__ temp) {
  float tc = temp[0];
  tc = fminf(fmaxf(tc, -5.0f), 5.0f);
  return expf(tc);
}

// insert into sorted (ascending key) top-8; strict < => on equal keys the
// earlier-arrived (smaller j, given ascending-j arrival) entry stays ahead.
__device__ __forceinline__ void ins_strict(float* kk, int* kj, float key, int j) {
  if (key < kk[KK - 1]) {
    kk[KK - 1] = key; kj[KK - 1] = j;
#pragma unroll
    for (int m = KK - 1; m > 0; --m) {
      if (kk[m] < kk[m - 1]) {
        float tk = kk[m]; kk[m] = kk[m - 1]; kk[m - 1] = tk;
        int tj = kj[m]; kj[m] = kj[m - 1]; kj[m - 1] = tj;
      }
    }
  }
}

// lexicographic (key asc, idx asc) insertion — arrival order independent.
__device__ __forceinline__ void ins_lex(float* kk, int* kj, float key, int j) {
  if (key < kk[KK - 1] || (key == kk[KK - 1] && j < kj[KK - 1])) {
    kk[KK - 1] = key; kj[KK - 1] = j;
#pragma unroll
    for (int m = KK - 1; m > 0; --m) {
      bool sw = (kk[m] < kk[m - 1]) || (kk[m] == kk[m - 1] && kj[m] < kj[m - 1]);
      if (sw) {
        float tk = kk[m]; kk[m] = kk[m - 1]; kk[m - 1] = tk;
        int tj = kj[m]; kj[m] = kj[m - 1]; kj[m - 1] = tj;
      }
    }
  }
}

__device__ __forceinline__ void scatter16(float (*dst)[64], int dc, int col,
                                          const float4& a, const float4& b,
                                          const float4& c, const float4& d) {
  dst[dc + 0][col] = a.x; dst[dc + 1][col] = a.y; dst[dc + 2][col] = a.z; dst[dc + 3][col] = a.w;
  dst[dc + 4][col] = b.x; dst[dc + 5][col] = b.y; dst[dc + 6][col] = b.z; dst[dc + 7][col] = b.w;
  dst[dc + 8][col] = c.x; dst[dc + 9][col] = c.y; dst[dc + 10][col] = c.z; dst[dc + 11][col] = c.w;
  dst[dc + 12][col] = d.x; dst[dc + 13][col] = d.y; dst[dc + 14][col] = d.z; dst[dc + 15][col] = d.w;
}

// ---------------- Kernel 1: MLP (3 layers) + row squared norms ----------------
__device__ __forceinline__ void mlp_layer(const float (*bin)[68], float (*bout)[68],
                                          float (*wT)[68], float* bias,
                                          const float* __restrict__ Wg,
                                          const float* __restrict__ bg,
                                          bool dorelu, int t) {
  const int rr = t >> 2;
  const int dc = (t & 3) << 4;
  {
    const float* wsrc = Wg + rr * DD + dc;
#pragma unroll
    for (int q = 0; q < 16; ++q) wT[dc + q][rr] = wsrc[q];  // wT[i][o] = W[o][i]
    if (t < DD) bias[t] = bg[t];
  }
  __syncthreads();
  const int tg = t & 15, og = t >> 4;
  float acc[4][4];
#pragma unroll
  for (int r = 0; r < 4; ++r)
#pragma unroll
    for (int c = 0; c < 4; ++c) acc[r][c] = 0.f;
#pragma unroll 4
  for (int i = 0; i < DD; ++i) {
    const float4 av = *reinterpret_cast<const float4*>(&bin[i][tg << 2]);
    const float4 wv = *reinterpret_cast<const float4*>(&wT[i][og << 2]);
    float aa[4] = {av.x, av.y, av.z, av.w};
    float ww[4] = {wv.x, wv.y, wv.z, wv.w};
#pragma unroll
    for (int r = 0; r < 4; ++r)
#pragma unroll
      for (int c = 0; c < 4; ++c) acc[r][c] += aa[r] * ww[c];
  }
#pragma unroll
  for (int r = 0; r < 4; ++r)
#pragma unroll
    for (int c = 0; c < 4; ++c) {
      float v = acc[r][c] + bias[(og << 2) + c];
      if (dorelu) v = fmaxf(v, 0.f);
      bout[(og << 2) + c][(tg << 2) + r] = v;  // transposed for next layer
    }
  __syncthreads();
}

__global__ __launch_bounds__(256) void k_mlp(
    const float* __restrict__ x,
    const float* __restrict__ W1, const float* __restrict__ b1,
    const float* __restrict__ W2, const float* __restrict__ b2,
    const float* __restrict__ W3, const float* __restrict__ b3,
    float* __restrict__ h, float* __restrict__ sqo) {
  __shared__ float bufA[DD][68];
  __shared__ float bufB[DD][68];
  __shared__ float wT[DD][68];
  __shared__ float bias[DD];
  const int t = threadIdx.x;
  const size_t tok0 = (size_t)blockIdx.x * 64;
  const int rr = t >> 2;
  const int dc = (t & 3) << 4;
  {
    const float* src = x + (tok0 + rr) * DD + dc;
#pragma unroll
    for (int q = 0; q < 16; ++q) bufA[dc + q][rr] = src[q];
  }
  mlp_layer(bufA, bufB, wT, bias, W1, b1, true, t);
  mlp_layer(bufB, bufA, wT, bias, W2, b2, true, t);
  mlp_layer(bufA, bufB, wT, bias, W3, b3, false, t);
  {
    float s = 0.f;
    float* dst = h + (tok0 + rr) * DD + dc;
#pragma unroll
    for (int q = 0; q < 16; ++q) {
      float v = bufB[dc + q][rr];
      dst[q] = v;
      s += v * v;
    }
    s += __shfl_xor(s, 1);
    s += __shfl_xor(s, 2);
    if ((t & 3) == 0) sqo[tok0 + rr] = s;
  }
}

// ------- Kernel 2: fused distance tiles + per-row top-8, register lists -------
__global__ __launch_bounds__(256, 3) void k_disttopk(
    const float* __restrict__ h, const float* __restrict__ sq,
    const float* __restrict__ temp,
    float* __restrict__ pk, int* __restrict__ pj) {
  // LDS: hiT [64][64] (16KB) | hjT [2][64][64] (32KB) | sqj [2][64] (512B)
  // merge phase reuses: dumps (32KB over hjT), stage-A out (8KB over hiT)
  __shared__ __align__(16) char smem[16384 + 32768 + 512];
  float (*hiT)[64] = (float (*)[64])(smem);
  float (*hjT0)[64] = (float (*)[64])(smem + 16384);
  float (*hjT1)[64] = (float (*)[64])(smem + 16384 + 16384);
  float* sqjS = (float*)(smem + 49152);  // [2][64]

  const int t = threadIdx.x;
  const int bx = blockIdx.x;
  const int b = bx >> 8;
  const int rem = bx & 255;
  const int rt = rem >> 2;
  const int ch = rem & 3;
  const int i0 = rt << 6;
  const int jbase = ch * (NN / CH);
  const float* hb = h + (size_t)b * NN * DD;
  const float* sqb = sq + b * NN;
  const float tau = tau_of(temp);

  const int og = t & 15, tg = t >> 4;
  const int r0 = tg << 2, c0 = og << 2;
  const int rr = t >> 2;
  const int dc = (t & 3) << 4;

  // stage hiT and tile 0 of hjT
  {
    const float* src = hb + (size_t)(i0 + rr) * DD + dc;
    float4 f0 = *(const float4*)(src);
    float4 f1 = *(const float4*)(src + 4);
    float4 f2 = *(const float4*)(src + 8);
    float4 f3 = *(const float4*)(src + 12);
    scatter16(hiT, dc, rr, f0, f1, f2, f3);
  }
  {
    const float* src = hb + (size_t)(jbase + rr) * DD + dc;
    float4 f0 = *(const float4*)(src);
    float4 f1 = *(const float4*)(src + 4);
    float4 f2 = *(const float4*)(src + 8);
    float4 f3 = *(const float4*)(src + 12);
    scatter16(hjT0, dc, rr, f0, f1, f2, f3);
    if (t < 64) sqjS[t] = sqb[jbase + t];
  }
  float sqi_r[4];
#pragma unroll
  for (int r = 0; r < 4; ++r) sqi_r[r] = sqb[i0 + r0 + r];

  float kk[4][KK]; int kj[4][KK];
#pragma unroll
  for (int r = 0; r < 4; ++r)
#pragma unroll
    for (int m = 0; m < KK; ++m) { kk[r][m] = 3.0e38f; kj[r][m] = 0x7fffffff; }

  __syncthreads();

  for (int jt = 0; jt < NT; ++jt) {
    const int p = jt & 1;
    const int j0 = jbase + (jt << 6);
    float (*cur)[64] = p ? hjT1 : hjT0;
    float (*nxt)[64] = p ? hjT0 : hjT1;
    const float* sqc = sqjS + p * 64;

    // T14: issue next tile's global loads now; write to LDS after compute
    float4 pf0, pf1, pf2, pf3; float psq = 0.f;
    const bool hasNext = (jt + 1 < NT);
    if (hasNext) {
      const float* src = hb + (size_t)(j0 + 64 + rr) * DD + dc;
      pf0 = *(const float4*)(src);
      pf1 = *(const float4*)(src + 4);
      pf2 = *(const float4*)(src + 8);
      pf3 = *(const float4*)(src + 12);
      if (t < 64) psq = sqb[j0 + 64 + t];
    }

    float acc[4][4];
#pragma unroll
    for (int r = 0; r < 4; ++r)
#pragma unroll
      for (int c = 0; c < 4; ++c) acc[r][c] = 0.f;
#pragma unroll 8
    for (int d = 0; d < DD; ++d) {
      const float4 xv = *(const float4*)(&hiT[d][r0]);
      const float4 bv = *(const float4*)(&cur[d][c0]);
      float aa[4] = {xv.x, xv.y, xv.z, xv.w};
      float wwv[4] = {bv.x, bv.y, bv.z, bv.w};
#pragma unroll
      for (int r = 0; r < 4; ++r)
#pragma unroll
        for (int c = 0; c < 4; ++c) acc[r][c] += aa[r] * wwv[c];
    }
    // epilogue: dist -> key -> per-row register top-8 (ascending j per thread)
    float sqjv[4];
#pragma unroll
    for (int c = 0; c < 4; ++c) sqjv[c] = sqc[c0 + c];
#pragma unroll
    for (int r = 0; r < 4; ++r) {
#pragma unroll
      for (int c = 0; c < 4; ++c) {
        float dist = __fsub_rn(__fadd_rn(sqi_r[r], sqjv[c]), __fmul_rn(2.0f, acc[r][c]));
        float key = __fmul_rn(dist, tau);
        ins_strict(kk[r], kj[r], key, j0 + c0 + c);
      }
    }
    if (hasNext) {
      scatter16(nxt, dc, rr, pf0, pf1, pf2, pf3);
      if (t < 64) sqjS[(p ^ 1) * 64 + t] = psq;
    }
    __syncthreads();
  }

  // ---- merge per-row across the 16 og-lists (2-stage, 2 row-slices/pass) ----
  // NOTE: pass loop MUST be unrolled so kk[r]/kj[r] indices stay compile-time
  // (rule #20: runtime-indexed register arrays demote to scratch).
  float* dK = (float*)(smem + 16384);            // [32][16][8] keys  (16KB)
  int*   dJ = (int*)(smem + 16384 + 16384);      // [32][16][8] idx   (16KB)
  float* oK = (float*)(smem);                    // [32][4][8] keys   (4KB)
  int*   oJ = (int*)(smem + 4096);               // [32][4][8] idx    (4KB)

#pragma unroll
  for (int pass = 0; pass < 2; ++pass) {
    __syncthreads();
#pragma unroll
    for (int rr2 = 0; rr2 < 2; ++rr2) {
      const int r = 2 * pass + rr2;
      const int lr = tg * 2 + rr2;
#pragma unroll
      for (int m = 0; m < KK; ++m) {
        dK[(lr * 16 + og) * KK + m] = kk[r][m];
        dJ[(lr * 16 + og) * KK + m] = kj[r][m];
      }
    }
    __syncthreads();
    if (t < 128) {
      const int lr = t >> 2, q = t & 3;
      float fk[KK]; int fj[KK];
#pragma unroll
      for (int m = 0; m < KK; ++m) { fk[m] = 3.0e38f; fj[m] = 0x7fffffff; }
#pragma unroll
      for (int o2 = 0; o2 < 4; ++o2) {
#pragma unroll
        for (int m = 0; m < KK; ++m) {
          ins_lex(fk, fj, dK[(lr * 16 + 4 * q + o2) * KK + m],
                          dJ[(lr * 16 + 4 * q + o2) * KK + m]);
        }
      }
#pragma unroll
      for (int m = 0; m < KK; ++m) {
        oK[(lr * 4 + q) * KK + m] = fk[m];
        oJ[(lr * 4 + q) * KK + m] = fj[m];
      }
    }
    __syncthreads();
    if (t < 32) {
      const int lr = t;
      const int row = 4 * (lr >> 1) + 2 * pass + (lr & 1);
      float fk[KK]; int fj[KK];
#pragma unroll
      for (int m = 0; m < KK; ++m) { fk[m] = 3.0e38f; fj[m] = 0x7fffffff; }
#pragma unroll
      for (int q2 = 0; q2 < 4; ++q2) {
#pragma unroll
        for (int m = 0; m < KK; ++m) {
          ins_lex(fk, fj, oK[(lr * 4 + q2) * KK + m], oJ[(lr * 4 + q2) * KK + m]);
        }
      }
      const size_t base = ((size_t)(b * NN + i0 + row) * CH + ch) * KK;
#pragma unroll
      for (int m = 0; m < KK; ++m) { pk[base + m] = fk[m]; pj[base + m] = fj[m]; }
    }
  }
}

// ------- Kernel 3: merge chunks, recompute dng, emit edges + logprobs -------
__global__ __launch_bounds__(256) void k_final(
    const float* __restrict__ h, const float* __restrict__ pk,
    const int* __restrict__ pj, const float* __restrict__ temp,
    float* __restrict__ out) {
  const int gid = blockIdx.x * 256 + threadIdx.x;  // 0..B*N-1
  const int b = gid >> 12;
  const int i = gid & (NN - 1);
  const float tau = tau_of(temp);

  float fk[KK]; int fj[KK];
#pragma unroll
  for (int m = 0; m < KK; ++m) { fk[m] = 3.0e38f; fj[m] = 0x7fffffff; }
  const size_t base = (size_t)(b * NN + i) * CH * KK;
#pragma unroll
  for (int s = 0; s < CH * KK; ++s) {
    ins_lex(fk, fj, pk[base + s], pj[base + s]);
  }

  const float* hi = h + (size_t)(b * NN + i) * DD;
  float4 xi[16];
#pragma unroll
  for (int q = 0; q < 16; ++q) xi[q] = *reinterpret_cast<const float4*>(hi + (q << 2));

  float* oute = out;
  float* outl = out + (size_t)BB * NN * KK * 2;
#pragma unroll
  for (int m = 0; m < KK; ++m) {
    const int j = fj[m];
    const float* hj = h + (size_t)(b * NN + j) * DD;
    float dng = 0.f;
#pragma unroll
    for (int q = 0; q < 16; ++q) {
      const float4 vj = *reinterpret_cast<const float4*>(hj + (q << 2));
      float dx = xi[q].x - vj.x; dng += dx * dx;
      float dy = xi[q].y - vj.y; dng += dy * dy;
      float dz = xi[q].z - vj.z; dng += dz * dz;
      float dw = xi[q].w - vj.w; dng += dw * dw;
    }
    const size_t e = (size_t)(b * NN + i) * KK + m;
    oute[e * 2 + 0] = (float)j;
    oute[e * 2 + 1] = (float)i;
    outl[e] = -__fmul_rn(dng, tau);
  }
}

extern "C" void kernel_launch(void* const* d_in, const int* in_sizes, int n_in,
                              void* d_out, int out_size, void* d_ws, size_t ws_size,
                              hipStream_t stream) {
  const float* x  = (const float*)d_in[0];
  const float* W1 = (const float*)d_in[1];
  const float* b1 = (const float*)d_in[2];
  const float* W2 = (const float*)d_in[3];
  const float* b2 = (const float*)d_in[4];
  const float* W3 = (const float*)d_in[5];
  const float* b3 = (const float*)d_in[6];
  const float* temp = (const float*)d_in[7];
  (void)in_sizes; (void)n_in; (void)out_size; (void)ws_size;

  float* ws = (float*)d_ws;
  float* h  = ws;                                       // B*N*D
  float* sq = h + (size_t)BB * NN * DD;                 // B*N
  float* pk = sq + (size_t)BB * NN;                     // B*N*CH*K
  int*   pj = (int*)(pk + (size_t)BB * NN * CH * KK);   // B*N*CH*K
  float* out = (float*)d_out;

  k_mlp<<<BB * NN / 64, 256, 0, stream>>>(x, W1, b1, W2, b2, W3, b3, h, sq);
  k_disttopk<<<BB * (NN / 64) * CH, 256, 0, stream>>>(h, sq, temp, pk, pj);
  k_final<<<BB * NN / 256, 256, 0, stream>>>(h, pk, pj, temp, out);
}

// Round 4
// 307.802 us; speedup vs baseline: 2.2106x; 2.2106x over previous
//
#include <hip/hip_runtime.h>
#include <math.h>

#define BB 4
#define NN 4096
#define DD 64
#define KK 8
#define CH 4                    // j-chunks per row: grid = 4*64*4 = 1024 blocks
#define NT ((NN / CH) / 64)     // 16 j-tiles per block

__device__ __forceinline__ float tau_of(const float* __restrict__ temp) {
  float tc = temp[0];
  tc = fminf(fmaxf(tc, -5.0f), 5.0f);
  return expf(tc);
}

// insert into sorted (ascending key) top-8; strict < => on equal keys the
// earlier-arrived (smaller j, given ascending-j arrival) entry stays ahead.
// NOTE: reference-to-1-D-array signature is load-bearing: pointer-decay off
// 2-D arrays blocked SROA in rounds 2/3 -> 300 MB of scratch traffic.
__device__ __forceinline__ void ins_strict(float (&kk)[KK], int (&kj)[KK], float key, int j) {
  if (key < kk[KK - 1]) {
    kk[KK - 1] = key; kj[KK - 1] = j;
#pragma unroll
    for (int m = KK - 1; m > 0; --m) {
      if (kk[m] < kk[m - 1]) {
        float tk = kk[m]; kk[m] = kk[m - 1]; kk[m - 1] = tk;
        int tj = kj[m]; kj[m] = kj[m - 1]; kj[m - 1] = tj;
      }
    }
  }
}

// lexicographic (key asc, idx asc) insertion — arrival order independent.
__device__ __forceinline__ void ins_lex(float (&kk)[KK], int (&kj)[KK], float key, int j) {
  if (key < kk[KK - 1] || (key == kk[KK - 1] && j < kj[KK - 1])) {
    kk[KK - 1] = key; kj[KK - 1] = j;
#pragma unroll
    for (int m = KK - 1; m > 0; --m) {
      bool sw = (kk[m] < kk[m - 1]) || (kk[m] == kk[m - 1] && kj[m] < kj[m - 1]);
      if (sw) {
        float tk = kk[m]; kk[m] = kk[m - 1]; kk[m - 1] = tk;
        int tj = kj[m]; kj[m] = kj[m - 1]; kj[m - 1] = tj;
      }
    }
  }
}

__device__ __forceinline__ void scatter16(float (*dst)[64], int dc, int col,
                                          const float4& a, const float4& b,
                                          const float4& c, const float4& d) {
  dst[dc + 0][col] = a.x; dst[dc + 1][col] = a.y; dst[dc + 2][col] = a.z; dst[dc + 3][col] = a.w;
  dst[dc + 4][col] = b.x; dst[dc + 5][col] = b.y; dst[dc + 6][col] = b.z; dst[dc + 7][col] = b.w;
  dst[dc + 8][col] = c.x; dst[dc + 9][col] = c.y; dst[dc + 10][col] = c.z; dst[dc + 11][col] = c.w;
  dst[dc + 12][col] = d.x; dst[dc + 13][col] = d.y; dst[dc + 14][col] = d.z; dst[dc + 15][col] = d.w;
}

// ---------------- Kernel 1: MLP (3 layers) + row squared norms ----------------
__device__ __forceinline__ void mlp_layer(const float (*bin)[68], float (*bout)[68],
                                          float (*wT)[68], float* bias,
                                          const float* __restrict__ Wg,
                                          const float* __restrict__ bg,
                                          bool dorelu, int t) {
  const int rr = t >> 2;
  const int dc = (t & 3) << 4;
  {
    const float* wsrc = Wg + rr * DD + dc;
#pragma unroll
    for (int q = 0; q < 16; ++q) wT[dc + q][rr] = wsrc[q];  // wT[i][o] = W[o][i]
    if (t < DD) bias[t] = bg[t];
  }
  __syncthreads();
  const int tg = t & 15, og = t >> 4;
  float acc[4][4];
#pragma unroll
  for (int r = 0; r < 4; ++r)
#pragma unroll
    for (int c = 0; c < 4; ++c) acc[r][c] = 0.f;
#pragma unroll 4
  for (int i = 0; i < DD; ++i) {
    const float4 av = *reinterpret_cast<const float4*>(&bin[i][tg << 2]);
    const float4 wv = *reinterpret_cast<const float4*>(&wT[i][og << 2]);
    float aa[4] = {av.x, av.y, av.z, av.w};
    float ww[4] = {wv.x, wv.y, wv.z, wv.w};
#pragma unroll
    for (int r = 0; r < 4; ++r)
#pragma unroll
      for (int c = 0; c < 4; ++c) acc[r][c] += aa[r] * ww[c];
  }
#pragma unroll
  for (int r = 0; r < 4; ++r)
#pragma unroll
    for (int c = 0; c < 4; ++c) {
      float v = acc[r][c] + bias[(og << 2) + c];
      if (dorelu) v = fmaxf(v, 0.f);
      bout[(og << 2) + c][(tg << 2) + r] = v;  // transposed for next layer
    }
  __syncthreads();
}

__global__ __launch_bounds__(256) void k_mlp(
    const float* __restrict__ x,
    const float* __restrict__ W1, const float* __restrict__ b1,
    const float* __restrict__ W2, const float* __restrict__ b2,
    const float* __restrict__ W3, const float* __restrict__ b3,
    float* __restrict__ h, float* __restrict__ sqo) {
  __shared__ float bufA[DD][68];
  __shared__ float bufB[DD][68];
  __shared__ float wT[DD][68];
  __shared__ float bias[DD];
  const int t = threadIdx.x;
  const size_t tok0 = (size_t)blockIdx.x * 64;
  const int rr = t >> 2;
  const int dc = (t & 3) << 4;
  {
    const float* src = x + (tok0 + rr) * DD + dc;
#pragma unroll
    for (int q = 0; q < 16; ++q) bufA[dc + q][rr] = src[q];
  }
  mlp_layer(bufA, bufB, wT, bias, W1, b1, true, t);
  mlp_layer(bufB, bufA, wT, bias, W2, b2, true, t);
  mlp_layer(bufA, bufB, wT, bias, W3, b3, false, t);
  {
    float s = 0.f;
    float* dst = h + (tok0 + rr) * DD + dc;
#pragma unroll
    for (int q = 0; q < 16; ++q) {
      float v = bufB[dc + q][rr];
      dst[q] = v;
      s += v * v;
    }
    s += __shfl_xor(s, 1);
    s += __shfl_xor(s, 2);
    if ((t & 3) == 0) sqo[tok0 + rr] = s;
  }
}

// ------- Kernel 2: fused distance tiles + per-row top-8, register lists -------
// 2x8 register tile per thread: 2 rows (r0, r0+1) x 8 cols (c0..c0+7).
// Two named top-8 lists per thread (kkA/kjA for r0, kkB/kjB for r0+1).
__global__ __launch_bounds__(256, 3) void k_disttopk(
    const float* __restrict__ h, const float* __restrict__ sq,
    const float* __restrict__ temp,
    float* __restrict__ pk, int* __restrict__ pj) {
  // LDS (33 KB -> 4 blocks/CU): hiT [64][64] @0 | hjT [64][64] @16384 | sqj @32768
  // merge reuse: dK @0 (16KB), dJ @16384 (16KB); then oK @0 (4KB), oJ @4096 (4KB)
  __shared__ __align__(16) char smem[16384 + 16384 + 256];
  float (*hiT)[64] = (float (*)[64])(smem);
  float (*hjT)[64] = (float (*)[64])(smem + 16384);
  float* sqjS = (float*)(smem + 32768);  // [64]

  const int t = threadIdx.x;
  const int bx = blockIdx.x;
  const int b = bx >> 8;
  const int rem = bx & 255;
  const int rt = rem >> 2;
  const int ch = rem & 3;
  const int i0 = rt << 6;
  const int jbase = ch * (NN / CH);
  const float* hb = h + (size_t)b * NN * DD;
  const float* sqb = sq + b * NN;
  const float tau = tau_of(temp);

  const int rg = t >> 3;        // 0..31
  const int cg = t & 7;         // 0..7
  const int r0 = rg << 1;       // even row
  const int c0 = cg << 3;       // col block of 8
  const int rr = t >> 2;        // staging: token within tile
  const int dc = (t & 3) << 4;  // staging: 16-float chunk

  // stage hiT and tile 0 of hjT (transposed [d][tok])
  {
    const float* src = hb + (size_t)(i0 + rr) * DD + dc;
    float4 f0 = *(const float4*)(src);
    float4 f1 = *(const float4*)(src + 4);
    float4 f2 = *(const float4*)(src + 8);
    float4 f3 = *(const float4*)(src + 12);
    scatter16(hiT, dc, rr, f0, f1, f2, f3);
  }
  {
    const float* src = hb + (size_t)(jbase + rr) * DD + dc;
    float4 f0 = *(const float4*)(src);
    float4 f1 = *(const float4*)(src + 4);
    float4 f2 = *(const float4*)(src + 8);
    float4 f3 = *(const float4*)(src + 12);
    scatter16(hjT, dc, rr, f0, f1, f2, f3);
    if (t < 64) sqjS[t] = sqb[jbase + t];
  }
  const float sqi0 = sqb[i0 + r0];
  const float sqi1 = sqb[i0 + r0 + 1];

  float kkA[KK]; int kjA[KK];
  float kkB[KK]; int kjB[KK];
#pragma unroll
  for (int m = 0; m < KK; ++m) {
    kkA[m] = 3.0e38f; kjA[m] = 0x7fffffff;
    kkB[m] = 3.0e38f; kjB[m] = 0x7fffffff;
  }

  __syncthreads();

  for (int jt = 0; jt < NT; ++jt) {
    const int j0 = jbase + (jt << 6);

    // T14: issue next tile's global loads now; LDS write after the compute+barrier
    float4 pf0, pf1, pf2, pf3; float psq = 0.f;
    const bool hasNext = (jt + 1 < NT);
    if (hasNext) {
      const float* src = hb + (size_t)(j0 + 64 + rr) * DD + dc;
      pf0 = *(const float4*)(src);
      pf1 = *(const float4*)(src + 4);
      pf2 = *(const float4*)(src + 8);
      pf3 = *(const float4*)(src + 12);
      if (t < 64) psq = sqb[j0 + 64 + t];
    }

    float acc[2][8];
#pragma unroll
    for (int r = 0; r < 2; ++r)
#pragma unroll
      for (int c = 0; c < 8; ++c) acc[r][c] = 0.f;
#pragma unroll 8
    for (int d = 0; d < DD; ++d) {
      const float2 a2 = *(const float2*)(&hiT[d][r0]);
      const float4 b0 = *(const float4*)(&hjT[d][c0]);
      const float4 b1 = *(const float4*)(&hjT[d][c0 + 4]);
      float bb[8] = {b0.x, b0.y, b0.z, b0.w, b1.x, b1.y, b1.z, b1.w};
#pragma unroll
      for (int c = 0; c < 8; ++c) {
        acc[0][c] += a2.x * bb[c];
        acc[1][c] += a2.y * bb[c];
      }
    }
    // epilogue: dist -> key -> per-row register top-8 (ascending j per thread)
    const float4 sj0 = *(const float4*)(&sqjS[c0]);
    const float4 sj1 = *(const float4*)(&sqjS[c0 + 4]);
    float sj[8] = {sj0.x, sj0.y, sj0.z, sj0.w, sj1.x, sj1.y, sj1.z, sj1.w};
#pragma unroll
    for (int c = 0; c < 8; ++c) {
      const int j = j0 + c0 + c;
      float d0 = __fsub_rn(__fadd_rn(sqi0, sj[c]), __fmul_rn(2.0f, acc[0][c]));
      ins_strict(kkA, kjA, __fmul_rn(d0, tau), j);
      float d1 = __fsub_rn(__fadd_rn(sqi1, sj[c]), __fmul_rn(2.0f, acc[1][c]));
      ins_strict(kkB, kjB, __fmul_rn(d1, tau), j);
    }
    __syncthreads();  // everyone done reading hjT/sqjS
    if (hasNext) {
      scatter16(hjT, dc, rr, pf0, pf1, pf2, pf3);
      if (t < 64) sqjS[t] = psq;
    }
    __syncthreads();  // staged tile visible
  }

  // ---- merge per-row across the 8 cg-lists ----
  float* dK = (float*)(smem);            // [64][8][8] keys (16KB)
  int*   dJ = (int*)(smem + 16384);      // [64][8][8] idx  (16KB)
  // dump (hiT/hjT no longer needed; loop-end barrier covers us)
#pragma unroll
  for (int m = 0; m < KK; ++m) {
    dK[(r0 * 8 + cg) * KK + m] = kkA[m];
    dJ[(r0 * 8 + cg) * KK + m] = kjA[m];
    dK[((r0 + 1) * 8 + cg) * KK + m] = kkB[m];
    dJ[((r0 + 1) * 8 + cg) * KK + m] = kjB[m];
  }
  __syncthreads();

  // stage A: 128 threads, each merges 4 lists of one (row, half)
  float fk[KK]; int fj[KK];
#pragma unroll
  for (int m = 0; m < KK; ++m) { fk[m] = 3.0e38f; fj[m] = 0x7fffffff; }
  const int rowA = t >> 1, half = t & 1;
  if (t < 128) {
#pragma unroll
    for (int o = 0; o < 4; ++o) {
#pragma unroll
      for (int m = 0; m < KK; ++m) {
        ins_lex(fk, fj, dK[(rowA * 8 + half * 4 + o) * KK + m],
                        dJ[(rowA * 8 + half * 4 + o) * KK + m]);
      }
    }
  }
  __syncthreads();  // stage-A reads complete before overwrite
  float* oK = (float*)(smem);            // [64][2][8] keys (4KB)
  int*   oJ = (int*)(smem + 4096);       // [64][2][8] idx  (4KB)
  if (t < 128) {
#pragma unroll
    for (int m = 0; m < KK; ++m) {
      oK[(rowA * 2 + half) * KK + m] = fk[m];
      oJ[(rowA * 2 + half) * KK + m] = fj[m];
    }
  }
  __syncthreads();

  // stage B: 64 threads, merge the 2 halves, write out
  if (t < 64) {
    float gk[KK]; int gj[KK];
#pragma unroll
    for (int m = 0; m < KK; ++m) { gk[m] = 3.0e38f; gj[m] = 0x7fffffff; }
#pragma unroll
    for (int q = 0; q < 2; ++q) {
#pragma unroll
      for (int m = 0; m < KK; ++m) {
        ins_lex(gk, gj, oK[(t * 2 + q) * KK + m], oJ[(t * 2 + q) * KK + m]);
      }
    }
    const size_t base = ((size_t)(b * NN + i0 + t) * CH + ch) * KK;
#pragma unroll
    for (int m = 0; m < KK; ++m) { pk[base + m] = gk[m]; pj[base + m] = gj[m]; }
  }
}

// ------- Kernel 3: merge chunks, recompute dng, emit edges + logprobs -------
__global__ __launch_bounds__(256) void k_final(
    const float* __restrict__ h, const float* __restrict__ pk,
    const int* __restrict__ pj, const float* __restrict__ temp,
    float* __restrict__ out) {
  const int gid = blockIdx.x * 256 + threadIdx.x;  // 0..B*N-1
  const int b = gid >> 12;
  const int i = gid & (NN - 1);
  const float tau = tau_of(temp);

  float fk[KK]; int fj[KK];
#pragma unroll
  for (int m = 0; m < KK; ++m) { fk[m] = 3.0e38f; fj[m] = 0x7fffffff; }
  const size_t base = (size_t)(b * NN + i) * CH * KK;
#pragma unroll
  for (int s = 0; s < CH * KK; ++s) {
    ins_lex(fk, fj, pk[base + s], pj[base + s]);
  }

  const float* hi = h + (size_t)(b * NN + i) * DD;
  float4 xi[16];
#pragma unroll
  for (int q = 0; q < 16; ++q) xi[q] = *reinterpret_cast<const float4*>(hi + (q << 2));

  float* oute = out;
  float* outl = out + (size_t)BB * NN * KK * 2;
#pragma unroll
  for (int m = 0; m < KK; ++m) {
    const int j = fj[m];
    const float* hj = h + (size_t)(b * NN + j) * DD;
    float dng = 0.f;
#pragma unroll
    for (int q = 0; q < 16; ++q) {
      const float4 vj = *reinterpret_cast<const float4*>(hj + (q << 2));
      float dx = xi[q].x - vj.x; dng += dx * dx;
      float dy = xi[q].y - vj.y; dng += dy * dy;
      float dz = xi[q].z - vj.z; dng += dz * dz;
      float dw = xi[q].w - vj.w; dng += dw * dw;
    }
    const size_t e = (size_t)(b * NN + i) * KK + m;
    oute[e * 2 + 0] = (float)j;
    oute[e * 2 + 1] = (float)i;
    outl[e] = -__fmul_rn(dng, tau);
  }
}

extern "C" void kernel_launch(void* const* d_in, const int* in_sizes, int n_in,
                              void* d_out, int out_size, void* d_ws, size_t ws_size,
                              hipStream_t stream) {
  const float* x  = (const float*)d_in[0];
  const float* W1 = (const float*)d_in[1];
  const float* b1 = (const float*)d_in[2];
  const float* W2 = (const float*)d_in[3];
  const float* b2 = (const float*)d_in[4];
  const float* W3 = (const float*)d_in[5];
  const float* b3 = (const float*)d_in[6];
  const float* temp = (const float*)d_in[7];
  (void)in_sizes; (void)n_in; (void)out_size; (void)ws_size;

  float* ws = (float*)d_ws;
  float* h  = ws;                                       // B*N*D
  float* sq = h + (size_t)BB * NN * DD;                 // B*N
  float* pk = sq + (size_t)BB * NN;                     // B*N*CH*K
  int*   pj = (int*)(pk + (size_t)BB * NN * CH * KK);   // B*N*CH*K
  float* out = (float*)d_out;

  k_mlp<<<BB * NN / 64, 256, 0, stream>>>(x, W1, b1, W2, b2, W3, b3, h, sq);
  k_disttopk<<<BB * (NN / 64) * CH, 256, 0, stream>>>(h, sq, temp, pk, pj);
  k_final<<<BB * NN / 256, 256, 0, stream>>>(h, pk, pj, temp, out);
}